// Round 9
// baseline (103.321 us; speedup 1.0000x reference)
//
#include <hip/hip_runtime.h>

typedef __attribute__((ext_vector_type(8))) short bf16x8;
typedef __attribute__((ext_vector_type(4))) float f32x4;
typedef __attribute__((ext_vector_type(4))) unsigned int u32x4;

#define NB 64
#define SQ 198
#define SKV 206
#define DM 768
#define NH 12
#define NROWS (NB * SKV)   // 13184
#define NCOL 2304          // Q | K | V columns

static __device__ __forceinline__ unsigned short f2b(float f) {
  union { float f; unsigned u; } v; v.f = f;
  unsigned r = v.u + 0x7FFFu + ((v.u >> 16) & 1u);
  return (unsigned short)(r >> 16);
}

typedef const __attribute__((address_space(1))) unsigned int g_u32;
typedef __attribute__((address_space(3))) unsigned int l_u32;
static __device__ __forceinline__ void gload_lds16(const void* g, void* l) {
  __builtin_amdgcn_global_load_lds((g_u32*)g, (l_u32*)l, 16, 0, 0);
}

// ---------- build bf16 Xkv[13184][768] ----------
__global__ __launch_bounds__(256) void k_conv_x(const float* __restrict__ hid,
                                                const float* __restrict__ mem,
                                                unsigned short* __restrict__ xkv) {
  int idx = (blockIdx.x * 256 + threadIdx.x) * 8;
  int r = idx / DM;
  int c = idx - r * DM;
  int b = r / SKV, s = r - b * SKV;
  const float* src = (s < SQ) ? (hid + (b * SQ + s) * DM + c)
                              : (mem + (s - SQ) * DM + c);
  float4 v0 = ((const float4*)src)[0];
  float4 v1 = ((const float4*)src)[1];
  unsigned w0 = f2b(v0.x) | ((unsigned)f2b(v0.y) << 16);
  unsigned w1 = f2b(v0.z) | ((unsigned)f2b(v0.w) << 16);
  unsigned w2 = f2b(v1.x) | ((unsigned)f2b(v1.y) << 16);
  unsigned w3 = f2b(v1.z) | ((unsigned)f2b(v1.w) << 16);
  u32x4 o = {w0, w1, w2, w3};
  *(u32x4*)(xkv + idx) = o;
}

// ---------- transpose W -> bf16 Wt[w][n][k] ----------
__global__ __launch_bounds__(256) void k_conv_w(const float* __restrict__ Wq,
                                                const float* __restrict__ Wk,
                                                const float* __restrict__ Wv,
                                                unsigned short* __restrict__ wt) {
  __shared__ float L[64][65];
  int w = blockIdx.z;
  int n0 = blockIdx.x * 64, k0 = blockIdx.y * 64;
  const float* W = (w == 0) ? Wq : (w == 1) ? Wk : Wv;
  int tid = threadIdx.x;
#pragma unroll
  for (int i = 0; i < 16; ++i) {
    int idx = i * 256 + tid;
    int lr = idx >> 6, lc = idx & 63;
    L[lr][lc] = W[(k0 + lr) * DM + n0 + lc];
  }
  __syncthreads();
  unsigned short* dst = wt + w * DM * DM;
#pragma unroll
  for (int o = 0; o < 2; ++o) {
    int gi = o * 256 + tid;
    int rn = gi >> 3, g = gi & 7;
    unsigned wrd[4];
#pragma unroll
    for (int jj = 0; jj < 4; ++jj) {
      float f0 = L[g * 8 + jj * 2 + 0][rn];
      float f1 = L[g * 8 + jj * 2 + 1][rn];
      wrd[jj] = f2b(f0) | ((unsigned)f2b(f1) << 16);
    }
    u32x4 o4 = {wrd[0], wrd[1], wrd[2], wrd[3]};
    *(u32x4*)(dst + (n0 + rn) * DM + k0 + g * 8) = o4;
  }
}

// ---------- fused QKV GEMM v6: m201-style 8-phase, 256x256, BK=64, 2 dbuf ----------
// LDS: A dbuf0 [0,32K) dbuf1 [32K,64K); B dbuf0 [64K,96K) dbuf1 [96K,128K).
// Rows 128B (64 bf16), granule swizzle phys = lg ^ (row&7) (zero-conflict, R7-family).
// Per K-tile 4 phases: Q1{12 rd, stage Ah1(t+1)} Q2{4 rd} Q3{8 rd, stage Bh0(t+2)}
// Q4{0 rd, stage Bh1+Ah0(t+2), vmcnt(6)}. Each phase: reads;stage;BAR;lgkm0;MFMA;BAR.
__global__ __launch_bounds__(512, 2) void k_gemm(const unsigned short* __restrict__ xkv,
                                                 const unsigned short* __restrict__ wt,
                                                 const float* __restrict__ bq,
                                                 const float* __restrict__ bk,
                                                 const float* __restrict__ bv,
                                                 unsigned short* __restrict__ cout) {
  __shared__ __align__(16) unsigned char smem[131072];
  // bijective XCD swizzle (nwg=468: q=58, r=4)
  int o = blockIdx.x, xcd = o & 7, rest = o >> 3;
  int sid = (xcd < 4 ? xcd * 59 : 236 + (xcd - 4) * 58) + rest;
  int mtile = sid / 9, ntile = sid - mtile * 9;
  int row0 = mtile * 256, col0 = ntile * 256;
  int w = ntile / 3;
  int colw0 = (ntile - w * 3) * 256;
  int tid = threadIdx.x, lane = tid & 63, wid = tid >> 6;
  int wm = wid >> 2, wn = wid & 3;      // 2M x 4N waves, each 128x64 out
  int l = lane & 15, gq = lane >> 4;
  const unsigned short* wbase = wt + w * DM * DM;

  // staging pointers: thread covers granule j*512+tid of each 16KB half-tile
  // granule s: row = s>>3, pg = s&7, source k-granule = pg ^ (row&7)
  const unsigned short* aPtr[2][2];
  const unsigned short* bPtr[2][2];
  {
    int srow = tid >> 3;                    // + j*64 per load
    int sg = (tid & 7) ^ (srow & 7);        // j*64, h*128 ≡ 0 mod 8
#pragma unroll
    for (int h = 0; h < 2; ++h)
#pragma unroll
      for (int j = 0; j < 2; ++j) {
        int ra = row0 + h * 128 + j * 64 + srow;
        if (ra > NROWS - 1) ra = NROWS - 1;
        aPtr[h][j] = xkv + ra * DM + sg * 8;
        bPtr[h][j] = wbase + (colw0 + h * 128 + j * 64 + srow) * DM + sg * 8;
      }
  }
  int ldsW = wid * 1024;                    // wave-uniform (HW adds lane*16)

#define STAGE_A(t, h)                                                                   \
  { gload_lds16(aPtr[h][0] + (t) * 64, smem + ((t) & 1) * 32768 + (h) * 16384 + ldsW);  \
    gload_lds16(aPtr[h][1] + (t) * 64, smem + ((t) & 1) * 32768 + (h) * 16384 + 8192 + ldsW); }
#define STAGE_B(t, h)                                                                   \
  { gload_lds16(bPtr[h][0] + (t) * 64, smem + 65536 + ((t) & 1) * 32768 + (h) * 16384 + ldsW); \
    gload_lds16(bPtr[h][1] + (t) * 64, smem + 65536 + ((t) & 1) * 32768 + (h) * 16384 + 8192 + ldsW); }

  f32x4 zero = {0.f, 0.f, 0.f, 0.f};
  f32x4 acc[8][4];
#pragma unroll
  for (int i = 0; i < 8; ++i)
#pragma unroll
    for (int j = 0; j < 4; ++j) acc[i][j] = zero;

  // prologue: tile 0 full + tile 1 {Ah0, Bh0, Bh1}; Ah1(1) staged at Q1(0)
  STAGE_A(0, 0); STAGE_A(0, 1); STAGE_B(0, 0); STAGE_B(0, 1);
  STAGE_A(1, 0); STAGE_B(1, 0); STAGE_B(1, 1);
  asm volatile("s_waitcnt vmcnt(6)" ::: "memory");   // tile 0 landed
  __builtin_amdgcn_s_barrier();

  // read addressing
  int colsel0 = ((0 * 4 + gq) ^ (l & 7)) << 4;       // kc=0
  int colsel1 = ((1 * 4 + gq) ^ (l & 7)) << 4;       // kc=1
  int rowA = (wm * 128 + l) * 128;                   // + mi*2048
  int rowB = (wn * 64 + l) * 128;                    // + ni*2048

#pragma unroll 1
  for (int t = 0; t < 12; ++t) {
    const unsigned char* Ab = smem + (t & 1) * 32768;
    const unsigned char* Bb = smem + 65536 + (t & 1) * 32768;
    bf16x8 a0[4][2], a1[4][2], b0[2][2], b1[2][2];
    // ---- Q1: read a0 (m0-3) + b0 (n0-1); stage Ah1(t+1); MFMA m0-3 x n0-1 ----
#pragma unroll
    for (int mi = 0; mi < 4; ++mi) {
      a0[mi][0] = *(const bf16x8*)(Ab + rowA + mi * 2048 + colsel0);
      a0[mi][1] = *(const bf16x8*)(Ab + rowA + mi * 2048 + colsel1);
    }
#pragma unroll
    for (int ni = 0; ni < 2; ++ni) {
      b0[ni][0] = *(const bf16x8*)(Bb + rowB + ni * 2048 + colsel0);
      b0[ni][1] = *(const bf16x8*)(Bb + rowB + ni * 2048 + colsel1);
    }
    if (t < 11) STAGE_A(t + 1, 1);
    __builtin_amdgcn_s_barrier();
    asm volatile("s_waitcnt lgkmcnt(0)" ::: "memory");
    __builtin_amdgcn_sched_barrier(0);
    __builtin_amdgcn_s_setprio(1);
#pragma unroll
    for (int mi = 0; mi < 4; ++mi)
#pragma unroll
      for (int ni = 0; ni < 2; ++ni) {
        acc[mi][ni] = __builtin_amdgcn_mfma_f32_16x16x32_bf16(a0[mi][0], b0[ni][0], acc[mi][ni], 0, 0, 0);
        acc[mi][ni] = __builtin_amdgcn_mfma_f32_16x16x32_bf16(a0[mi][1], b0[ni][1], acc[mi][ni], 0, 0, 0);
      }
    __builtin_amdgcn_s_setprio(0);
    __builtin_amdgcn_s_barrier();
    // ---- Q2: read b1 (n2-3); MFMA m0-3 x n2-3 ----
#pragma unroll
    for (int ni = 0; ni < 2; ++ni) {
      b1[ni][0] = *(const bf16x8*)(Bb + rowB + (2 + ni) * 2048 + colsel0);
      b1[ni][1] = *(const bf16x8*)(Bb + rowB + (2 + ni) * 2048 + colsel1);
    }
    __builtin_amdgcn_s_barrier();
    asm volatile("s_waitcnt lgkmcnt(0)" ::: "memory");
    __builtin_amdgcn_sched_barrier(0);
    __builtin_amdgcn_s_setprio(1);
#pragma unroll
    for (int mi = 0; mi < 4; ++mi)
#pragma unroll
      for (int ni = 0; ni < 2; ++ni) {
        acc[mi][2 + ni] = __builtin_amdgcn_mfma_f32_16x16x32_bf16(a0[mi][0], b1[ni][0], acc[mi][2 + ni], 0, 0, 0);
        acc[mi][2 + ni] = __builtin_amdgcn_mfma_f32_16x16x32_bf16(a0[mi][1], b1[ni][1], acc[mi][2 + ni], 0, 0, 0);
      }
    __builtin_amdgcn_s_setprio(0);
    __builtin_amdgcn_s_barrier();
    // ---- Q3: read a1 (m4-7); stage Bh0(t+2); MFMA m4-7 x n0-1 ----
#pragma unroll
    for (int mi = 0; mi < 4; ++mi) {
      a1[mi][0] = *(const bf16x8*)(Ab + rowA + (4 + mi) * 2048 + colsel0);
      a1[mi][1] = *(const bf16x8*)(Ab + rowA + (4 + mi) * 2048 + colsel1);
    }
    if (t < 10) STAGE_B(t + 2, 0);
    __builtin_amdgcn_s_barrier();
    asm volatile("s_waitcnt lgkmcnt(0)" ::: "memory");
    __builtin_amdgcn_sched_barrier(0);
    __builtin_amdgcn_s_setprio(1);
#pragma unroll
    for (int mi = 0; mi < 4; ++mi)
#pragma unroll
      for (int ni = 0; ni < 2; ++ni) {
        acc[4 + mi][ni] = __builtin_amdgcn_mfma_f32_16x16x32_bf16(a1[mi][0], b0[ni][0], acc[4 + mi][ni], 0, 0, 0);
        acc[4 + mi][ni] = __builtin_amdgcn_mfma_f32_16x16x32_bf16(a1[mi][1], b0[ni][1], acc[4 + mi][ni], 0, 0, 0);
      }
    __builtin_amdgcn_s_setprio(0);
    __builtin_amdgcn_s_barrier();
    // ---- Q4: stage Bh1+Ah0(t+2); MFMA m4-7 x n2-3; vmcnt; BAR ----
    if (t < 10) { STAGE_B(t + 2, 1); STAGE_A(t + 2, 0); }
    __builtin_amdgcn_s_barrier();
    __builtin_amdgcn_s_setprio(1);
#pragma unroll
    for (int mi = 0; mi < 4; ++mi)
#pragma unroll
      for (int ni = 0; ni < 2; ++ni) {
        acc[4 + mi][2 + ni] = __builtin_amdgcn_mfma_f32_16x16x32_bf16(a1[mi][0], b1[ni][0], acc[4 + mi][2 + ni], 0, 0, 0);
        acc[4 + mi][2 + ni] = __builtin_amdgcn_mfma_f32_16x16x32_bf16(a1[mi][1], b1[ni][1], acc[4 + mi][2 + ni], 0, 0, 0);
      }
    __builtin_amdgcn_s_setprio(0);
    if (t < 10)       { asm volatile("s_waitcnt vmcnt(6)" ::: "memory"); }
    else              { asm volatile("s_waitcnt vmcnt(0)" ::: "memory"); }
    __builtin_amdgcn_s_barrier();
  }
#undef STAGE_A
#undef STAGE_B

  // epilogue: bias + bf16 C via LDS (256 rows x 512B, (row&7)<<4 XOR)
  const float* bias = (w == 0) ? bq : (w == 1) ? bk : bv;
  float bb[4];
#pragma unroll
  for (int ni = 0; ni < 4; ++ni) bb[ni] = bias[colw0 + wn * 64 + ni * 16 + l];

  __syncthreads();
#pragma unroll
  for (int mi = 0; mi < 8; ++mi)
#pragma unroll
    for (int ni = 0; ni < 4; ++ni)
#pragma unroll
      for (int rr = 0; rr < 4; ++rr) {
        int row = wm * 128 + mi * 16 + gq * 4 + rr;
        int col = wn * 64 + ni * 16 + l;
        *(unsigned short*)(smem + row * 512 + ((col * 2) ^ ((row & 7) << 4))) =
            f2b(acc[mi][ni][rr] + bb[ni]);
      }
  __syncthreads();
#pragma unroll
  for (int it = 0; it < 16; ++it) {
    int gi = it * 512 + tid;
    int row = gi >> 5, gran = gi & 31;
    if (row0 + row < NROWS) {
      u32x4 v = *(const u32x4*)(smem + row * 512 + ((gran * 16) ^ ((row & 7) << 4)));
      *(u32x4*)(cout + (row0 + row) * NCOL + col0 + gran * 8) = v;
    }
  }
}

// ---------- attention (unchanged): swapped QK^T, in-register P, 52KB LDS ----------
static __device__ __forceinline__ int vt_off(int row, int col) {
  return row * 416 + ((col * 2) ^ (((row >> 3) & 1) << 4));
}

__global__ __launch_bounds__(256, 3) void k_attn(const unsigned short* __restrict__ cqkv,
                                                 float* __restrict__ out) {
  __shared__ __align__(16) unsigned short Ksh[208 * 64];
  __shared__ __align__(16) unsigned char  VtB[64 * 416];
  int bh = blockIdx.x;
  int b = bh / NH, h = bh - b * NH;
  int tid = threadIdx.x, lane = tid & 63, wid = tid >> 6;
  int g = lane >> 4, l = lane & 15;
  const unsigned short* Cb = cqkv + (b * SKV) * NCOL + h * 64;

  if (tid < 64) *(unsigned*)(VtB + vt_off(tid, 206)) = 0u;
  for (int i = tid; i < 208 * 8; i += 256) {
    int row = i >> 3, gg = i & 7;
    int srow = (row < SKV) ? row : (SKV - 1);
    u32x4 v = *(const u32x4*)(Cb + srow * NCOL + 768 + gg * 8);
    *(u32x4*)((unsigned char*)Ksh + ((row * 128 + gg * 16) ^ ((row & 7) << 4))) = v;
  }
  for (int i = tid; i < 206 * 8; i += 256) {
    int key = i >> 3, gg = i & 7;
    u32x4 v = *(const u32x4*)(Cb + key * NCOL + 1536 + gg * 8);
    union { u32x4 v4; unsigned short e[8]; } u; u.v4 = v;
#pragma unroll
    for (int j = 0; j < 8; ++j)
      *(unsigned short*)(VtB + vt_off(gg * 8 + j, key)) = u.e[j];
  }
  __syncthreads();

  const float scale = 0.125f;
  f32x4 zero4 = {0.f, 0.f, 0.f, 0.f};
  int srcA = ((g & 1) << 5) + l;
  int srcB = srcA + 16;
  bool hiHalf = (g >= 2);

  for (int qt = wid; qt < 13; qt += 4) {
    int qr = qt * 16 + l;
    int qld = qr > 197 ? 197 : qr;
    const unsigned short* qp = Cb + qld * NCOL + g * 8;
    bf16x8 qa0 = *(const bf16x8*)qp;
    bf16x8 qa1 = *(const bf16x8*)(qp + 32);

    f32x4 sc[13];
#pragma unroll
    for (int nt = 0; nt < 13; ++nt) sc[nt] = zero4;
#pragma unroll
    for (int nt = 0; nt < 13; ++nt) {
      int key = nt * 16 + l;
      int rb = key * 128, sw = (key & 7) << 4, kb = g * 16;
      bf16x8 kb0 = *(const bf16x8*)((const unsigned char*)Ksh + rb + (kb ^ sw));
      bf16x8 kb1 = *(const bf16x8*)((const unsigned char*)Ksh + rb + ((kb + 64) ^ sw));
      sc[nt] = __builtin_amdgcn_mfma_f32_16x16x32_bf16(kb0, qa0, sc[nt], 0, 0, 0);
      sc[nt] = __builtin_amdgcn_mfma_f32_16x16x32_bf16(kb1, qa1, sc[nt], 0, 0, 0);
    }

    float mx = -1e30f;
#pragma unroll
    for (int nt = 0; nt < 13; ++nt)
#pragma unroll
      for (int r = 0; r < 4; ++r) {
        int key = nt * 16 + g * 4 + r;
        float s = sc[nt][r] * scale;
        bool ok = (key < 197 || qr == 197) && (key < SKV);
        s = ok ? s : -1e30f;
        sc[nt][r] = s;
        mx = fmaxf(mx, s);
      }
    mx = fmaxf(mx, __shfl_xor(mx, 16));
    mx = fmaxf(mx, __shfl_xor(mx, 32));
    float sum = 0.f;
#pragma unroll
    for (int nt = 0; nt < 13; ++nt)
#pragma unroll
      for (int r = 0; r < 4; ++r) {
        float p = __expf(sc[nt][r] - mx);
        sc[nt][r] = p;
        sum += p;
      }
    sum += __shfl_xor(sum, 16);
    sum += __shfl_xor(sum, 32);
    float inv = 1.0f / sum;

    unsigned pk0[13], pk1[13];
#pragma unroll
    for (int nt = 0; nt < 13; ++nt) {
      asm("v_cvt_pk_bf16_f32 %0, %1, %2" : "=v"(pk0[nt]) : "v"(sc[nt][0]), "v"(sc[nt][1]));
      asm("v_cvt_pk_bf16_f32 %0, %1, %2" : "=v"(pk1[nt]) : "v"(sc[nt][2]), "v"(sc[nt][3]));
    }

    f32x4 ctx[4];
#pragma unroll
    for (int dt = 0; dt < 4; ++dt) ctx[dt] = zero4;
#pragma unroll
    for (int c = 0; c < 7; ++c) {
      union { unsigned w[4]; bf16x8 v; } pa;
      if (c < 6) {
        int n0 = 2 * c, n1 = 2 * c + 1;
        unsigned a0 = (unsigned)__shfl((int)pk0[n0], srcA), b0 = (unsigned)__shfl((int)pk0[n1], srcA);
        unsigned a1 = (unsigned)__shfl((int)pk1[n0], srcA), b1 = (unsigned)__shfl((int)pk1[n1], srcA);
        unsigned a2 = (unsigned)__shfl((int)pk0[n0], srcB), b2 = (unsigned)__shfl((int)pk0[n1], srcB);
        unsigned a3 = (unsigned)__shfl((int)pk1[n0], srcB), b3 = (unsigned)__shfl((int)pk1[n1], srcB);
        pa.w[0] = hiHalf ? b0 : a0;
        pa.w[1] = hiHalf ? b1 : a1;
        pa.w[2] = hiHalf ? b2 : a2;
        pa.w[3] = hiHalf ? b3 : a3;
      } else {
        unsigned a0 = (unsigned)__shfl((int)pk0[12], srcA);
        unsigned a1 = (unsigned)__shfl((int)pk1[12], srcA);
        unsigned a2 = (unsigned)__shfl((int)pk0[12], srcB);
        unsigned a3 = (unsigned)__shfl((int)pk1[12], srcB);
        pa.w[0] = hiHalf ? 0u : a0;
        pa.w[1] = hiHalf ? 0u : a1;
        pa.w[2] = hiHalf ? 0u : a2;
        pa.w[3] = hiHalf ? 0u : a3;
      }
      int colb = c * 32 + g * 8;
      if (c == 6 && hiHalf) colb = 0;
#pragma unroll
      for (int dt = 0; dt < 4; ++dt) {
        bf16x8 vb = *(const bf16x8*)(VtB + vt_off(dt * 16 + l, colb));
        ctx[dt] = __builtin_amdgcn_mfma_f32_16x16x32_bf16(pa.v, vb, ctx[dt], 0, 0, 0);
      }
    }

    float invr[4];
#pragma unroll
    for (int r = 0; r < 4; ++r) invr[r] = __shfl(inv, g * 4 + r);
#pragma unroll
    for (int dt = 0; dt < 4; ++dt)
#pragma unroll
      for (int r = 0; r < 4; ++r) {
        int qo = qt * 16 + g * 4 + r;
        if (qo < SQ)
          out[(b * SQ + qo) * DM + h * 64 + dt * 16 + l] = ctx[dt][r] * invr[r];
      }
  }
}

extern "C" void kernel_launch(void* const* d_in, const int* in_sizes, int n_in,
                              void* d_out, int out_size, void* d_ws, size_t ws_size,
                              hipStream_t stream) {
  const float* hid = (const float*)d_in[0];
  const float* mem = (const float*)d_in[1];
  const float* Wq  = (const float*)d_in[2];
  const float* bq  = (const float*)d_in[3];
  const float* Wk  = (const float*)d_in[4];
  const float* bk  = (const float*)d_in[5];
  const float* Wv  = (const float*)d_in[6];
  const float* bv  = (const float*)d_in[7];
  float* out = (float*)d_out;

  unsigned short* xkv  = (unsigned short*)d_ws;
  unsigned short* wt   = xkv + NROWS * DM;
  unsigned short* cbuf = wt + 3 * DM * DM;

  k_conv_x<<<dim3(NROWS * DM / 8 / 256), 256, 0, stream>>>(hid, mem, xkv);
  k_conv_w<<<dim3(12, 12, 3), 256, 0, stream>>>(Wq, Wk, Wv, wt);
  k_gemm<<<dim3(468), 512, 0, stream>>>(xkv, wt, bq, bk, bv, cbuf);
  k_attn<<<dim3(NB * NH), 256, 0, stream>>>(cbuf, out);
}